// Round 6
// baseline (786.219 us; speedup 1.0000x reference)
//
#include <hip/hip_runtime.h>
#include <hip/hip_bf16.h>
#include <cstdint>

#define B_ 2
#define S_ 2048
#define HID_ 2560
#define H_ 40
#define NOPE_ 64
#define ROPE_ 32
#define VD_ 64
#define QKD_ 96
#define QRANK_ 768
#define KVRANK_ 256
#define KVRP_ 288
#define KVRP_PAD 384
#define HQKD (H_*QKD_)          // 3840
#define HKV  (H_*(NOPE_+VD_))   // 5120
#define HVD  (H_*VD_)           // 2560
#define TOK  (B_*S_)            // 4096
#define EPS_ 1e-5f
#define SCALING_ 0.10206207261596575f
// SCALING_ * log2(e): scores scaled into log2 domain so softmax uses native exp2
#define SCALE2_ 0.14724506012928484f

typedef __bf16  bf16x8  __attribute__((ext_vector_type(8)));
typedef float   floatx4 __attribute__((ext_vector_type(4)));
typedef short   shortx4 __attribute__((ext_vector_type(4)));
typedef unsigned short ushort8_t __attribute__((ext_vector_type(8)));

__device__ __forceinline__ unsigned short f2bf(float f) {
    unsigned int u = __builtin_bit_cast(unsigned int, f);
    unsigned int r = (u + 0x7FFFu + ((u >> 16) & 1u)) >> 16;  // RNE
    return (unsigned short)r;
}
__device__ __forceinline__ float bf2f(unsigned short h) {
    return __builtin_bit_cast(float, ((unsigned int)h) << 16);
}
__device__ __forceinline__ float load_in(const void* p, long i, int bf) {
    if (bf) return bf2f(((const unsigned short*)p)[i]);
    return ((const float*)p)[i];
}

// async global->LDS, 16B per lane. LDS dest = wave-uniform base + lane*16.
__device__ __forceinline__ void gl_lds16(const unsigned short* g, unsigned short* l) {
    __builtin_amdgcn_global_load_lds(
        (const __attribute__((address_space(1))) unsigned int*)g,
        (__attribute__((address_space(3))) unsigned int*)l, 16, 0, 0);
}

// ---- dtype detector: cos[0]==1.0 -> f32 stores 0x0000 in first half-word,
// bf16 stores 0x3F80.
__global__ void k_detect(const unsigned short* cosb, int* flag) {
    if (threadIdx.x == 0) flag[0] = (cosb[0] != 0) ? 1 : 0;
}

__global__ void k_tobf(const void* in, unsigned short* out, long n, const int* flag) {
    int bf = flag[0];
    long i = (long)blockIdx.x * blockDim.x + threadIdx.x;
    if (i >= n) return;
    out[i] = bf ? ((const unsigned short*)in)[i] : f2bf(((const float*)in)[i]);
}

// ---- LDS-tiled transpose+cast: in [K][N] -> out bf16 [Npad][K], zero-fill n>=N
__global__ __launch_bounds__(256) void k_transpose(const void* in, unsigned short* out,
                                                   int K, int N, int Npad, const int* flag) {
    __shared__ float tile[32][33];
    int bf = flag[0];
    int k0 = blockIdx.x * 32;
    int n0 = blockIdx.y * 32;
    int tx = threadIdx.x & 31, ty = threadIdx.x >> 5;
#pragma unroll
    for (int i = 0; i < 4; i++) {
        int k = k0 + ty + 8 * i, n = n0 + tx;
        float v = 0.f;
        if (n < N && k < K) v = load_in(in, (long)k * N + n, bf);
        tile[ty + 8 * i][tx] = v;
    }
    __syncthreads();
#pragma unroll
    for (int i = 0; i < 4; i++) {
        int n = n0 + ty + 8 * i, k = k0 + tx;
        if (n < Npad && k < K) out[(long)n * K + k] = f2bf(tile[tx][ty + 8 * i]);
    }
}

// ---- transpose V out of kv_raw: [tok][h*128+64+vd] -> vt[(b*H+h)*64+vd][S]
__global__ __launch_bounds__(256) void k_vtrans(const unsigned short* kv, unsigned short* vt) {
    __shared__ unsigned short t[32][33];
    int bh = blockIdx.z;
    int s0 = blockIdx.x * 32, v0 = blockIdx.y * 32;
    int b = bh / H_, h = bh % H_;
    int tx = threadIdx.x & 31, ty = threadIdx.x >> 5;
#pragma unroll
    for (int i = 0; i < 4; i++) {
        int s = s0 + ty + 8 * i, vd = v0 + tx;
        t[ty + 8 * i][tx] = kv[((long)b * S_ + s) * HKV + h * 128 + 64 + vd];
    }
    __syncthreads();
#pragma unroll
    for (int i = 0; i < 4; i++) {
        int vd = v0 + ty + 8 * i, s = s0 + tx;
        vt[((long)bh * 64 + vd) * S_ + s] = t[tx][ty + 8 * i];
    }
}

// ---- RMSNorm
__global__ __launch_bounds__(256) void k_rmsnorm(const float* in, int ldin, int L,
                                                 const void* w, unsigned short* out,
                                                 int ldout, const int* flag) {
    int bf = flag[0];
    long row = blockIdx.x;
    const float* x = in + row * ldin;
    float ss = 0.f;
    for (int i = threadIdx.x; i < L; i += 256) { float v = x[i]; ss += v * v; }
    __shared__ float red[256];
    red[threadIdx.x] = ss;
    __syncthreads();
    for (int s = 128; s > 0; s >>= 1) {
        if (threadIdx.x < s) red[threadIdx.x] += red[threadIdx.x + s];
        __syncthreads();
    }
    float scale = rsqrtf(red[0] / (float)L + EPS_);
    for (int i = threadIdx.x; i < L; i += 256)
        out[row * ldout + i] = f2bf(x[i] * scale * load_in(w, i, bf));
}

// ---- RoPE on q (in-place, bf16)
__global__ void k_rope_q(unsigned short* q, const void* cosb, const void* sinb, const int* flag) {
    int bf = flag[0];
    long i = (long)blockIdx.x * blockDim.x + threadIdx.x;
    if (i >= (long)TOK * H_ * 16) return;
    int r = (int)(i & 15);
    long t = i >> 4;
    int h = (int)(t % H_);
    long tok = t / H_;
    int s = (int)(tok % S_);
    long base = tok * HQKD + h * QKD_ + NOPE_;
    float x1 = bf2f(q[base + r]), x2 = bf2f(q[base + 16 + r]);
    float c1 = load_in(cosb, (long)s * ROPE_ + r, bf);
    float s1 = load_in(sinb, (long)s * ROPE_ + r, bf);
    float c2 = load_in(cosb, (long)s * ROPE_ + 16 + r, bf);
    float s2 = load_in(sinb, (long)s * ROPE_ + 16 + r, bf);
    q[base + r]      = f2bf(x1 * c1 - x2 * s1);
    q[base + 16 + r] = f2bf(x2 * c2 + x1 * s2);
}

// ---- RoPE on shared k_rot
__global__ void k_rope_k(const float* ckv, unsigned short* krot,
                         const void* cosb, const void* sinb, const int* flag) {
    int bf = flag[0];
    long i = (long)blockIdx.x * blockDim.x + threadIdx.x;
    if (i >= (long)TOK * 16) return;
    int r = (int)(i & 15);
    long tok = i >> 4;
    int s = (int)(tok % S_);
    const float* x = ckv + tok * KVRP_PAD + KVRANK_;
    float x1 = x[r], x2 = x[16 + r];
    float c1 = load_in(cosb, (long)s * ROPE_ + r, bf);
    float s1 = load_in(sinb, (long)s * ROPE_ + r, bf);
    float c2 = load_in(cosb, (long)s * ROPE_ + 16 + r, bf);
    float s2 = load_in(sinb, (long)s * ROPE_ + 16 + r, bf);
    krot[tok * ROPE_ + r]      = f2bf(x1 * c1 - x2 * s1);
    krot[tok * ROPE_ + 16 + r] = f2bf(x2 * c2 + x1 * s2);
}

// ---- bf16 MFMA GEMM, m97 structure: unpadded LDS + global_load_lds width-16
__global__ __launch_bounds__(256) void k_gemm(const unsigned short* A, const unsigned short* Bt,
                                              void* C, int M, int N, int K,
                                              int out_mode, const int* flag) {
    int obf = (out_mode == 2) ? flag[0] : out_mode;
    __shared__ __align__(16) unsigned short As[128 * 32];
    __shared__ __align__(16) unsigned short Bs[128 * 32];
    int tid = threadIdx.x;
    int gm = blockIdx.y * 128, gn = blockIdx.x * 128;
    int lane = tid & 63, w = tid >> 6, wm = w >> 1, wn = w & 1;
    int g = lane >> 4, qi = lane & 15;
    int srow = lane >> 2;          // 0..15
    int scol = (lane & 3) * 8;     // 0,8,16,24
    const unsigned short* Ag0 = A  + (long)(gm + w * 16 + srow) * K + scol;
    const unsigned short* Ag1 = A  + (long)(gm + (w + 4) * 16 + srow) * K + scol;
    const unsigned short* Bg0 = Bt + (long)(gn + w * 16 + srow) * K + scol;
    const unsigned short* Bg1 = Bt + (long)(gn + (w + 4) * 16 + srow) * K + scol;
    unsigned short* Al0 = &As[w * 512];
    unsigned short* Al1 = &As[(w + 4) * 512];
    unsigned short* Bl0 = &Bs[w * 512];
    unsigned short* Bl1 = &Bs[(w + 4) * 512];

    floatx4 acc[4][4];
#pragma unroll
    for (int mt = 0; mt < 4; mt++)
#pragma unroll
        for (int nt = 0; nt < 4; nt++) acc[mt][nt] = (floatx4){0.f, 0.f, 0.f, 0.f};

    for (int k0 = 0; k0 < K; k0 += 32) {
        __syncthreads();
        gl_lds16(Ag0 + k0, Al0);
        gl_lds16(Ag1 + k0, Al1);
        gl_lds16(Bg0 + k0, Bl0);
        gl_lds16(Bg1 + k0, Bl1);
        __syncthreads();
        bf16x8 fa[4], fb[4];
#pragma unroll
        for (int mt = 0; mt < 4; mt++) fa[mt] = *(const bf16x8*)&As[(wm * 64 + mt * 16 + qi) * 32 + g * 8];
#pragma unroll
        for (int nt = 0; nt < 4; nt++) fb[nt] = *(const bf16x8*)&Bs[(wn * 64 + nt * 16 + qi) * 32 + g * 8];
#pragma unroll
        for (int mt = 0; mt < 4; mt++)
#pragma unroll
            for (int nt = 0; nt < 4; nt++)
                acc[mt][nt] = __builtin_amdgcn_mfma_f32_16x16x32_bf16(fa[mt], fb[nt], acc[mt][nt], 0, 0, 0);
    }
#pragma unroll
    for (int mt = 0; mt < 4; mt++)
#pragma unroll
        for (int nt = 0; nt < 4; nt++)
#pragma unroll
            for (int r = 0; r < 4; r++) {
                long row = gm + wm * 64 + mt * 16 + g * 4 + r;
                long col = gn + wn * 64 + nt * 16 + qi;
                float v = acc[mt][nt][r];
                if (obf) ((unsigned short*)C)[row * N + col] = f2bf(v);
                else     ((float*)C)[row * N + col] = v;
            }
}

// ---- flash attention v5: balanced pairing (R5) + double-buffered pipeline.
// K tiles stream global->LDS via async global_load_lds into the ping-pong
// buffer while the current tile computes; V prefetched global->reg->padded LDS.
// One barrier per tile; the barrier's vmcnt(0) drain is ~free because the
// async loads had the whole compute phase to land. exp2-domain softmax +
// __any-gated rescale skip cut the per-tile VALU chain.
__global__ __launch_bounds__(256) void k_attn(const unsigned short* q, const unsigned short* kv,
                                              const unsigned short* krot, const unsigned short* vt,
                                              unsigned short* out) {
    __shared__ __align__(16) unsigned short Ks[2][64 * 96];  // 2 x 12KB, key-major pass+rope
    __shared__ __align__(16) unsigned short Vs[2][64 * 80];  // 2 x 10KB, vd-major, pad->80
    int tid = threadIdx.x;
    int lane = tid & 63, w = tid >> 6;
    int b = blockIdx.z, h = blockIdx.y;
    int j = blockIdx.x;                      // 0..7
    int g = lane >> 4, qi = lane & 15;
    long tok0 = (long)b * S_;

    const unsigned short* kbase = kv + tok0 * HKV + h * 128;
    const unsigned short* krb   = krot + tok0 * ROPE_;
    const unsigned short* vtb   = vt + ((long)(b * H_ + h) * 64) * S_;

    // K async staging geometry: 768 8-short chunks; wave w owns chunks
    // [(w*3+i)*64 + lane]. row = chunk/12, cc = (chunk%12)*8; LDS linear = chunk*8.
    const unsigned short* ksrc0[3];
    int kstride[3];
#pragma unroll
    for (int i = 0; i < 3; i++) {
        int chunk = (w * 3 + i) * 64 + lane;
        int row = chunk / 12, cc = (chunk % 12) * 8;
        if (cc < 64) { ksrc0[i] = kbase + (long)row * HKV + cc;          kstride[i] = HKV; }
        else         { ksrc0[i] = krb   + (long)row * ROPE_ + (cc - 64); kstride[i] = ROPE_; }
    }
    // V reg-prefetch geometry: 512 chunks, thread owns {tid, tid+256}.
    const unsigned short* vsrc0[2];
    int vdst[2];
#pragma unroll
    for (int i = 0; i < 2; i++) {
        int idx = i * 256 + tid;
        int row = idx >> 3, cc = (idx & 7) * 8;
        vsrc0[i] = vtb + (long)row * S_ + cc;
        vdst[i] = row * 80 + cc;
    }

    for (int half = 0; half < 2; half++) {
        int qblk = half ? (15 - j) : j;
        int qbase = qblk * 128;
        int ktb = 2 * qblk + 2;
        int ktmax_w = (qbase + w * 32 + 31) >> 6;

        bf16x8 fq[2][3];
#pragma unroll
        for (int qt = 0; qt < 2; qt++) {
            const unsigned short* qp = q + (tok0 + qbase + w * 32 + qt * 16 + qi) * HQKD + h * QKD_;
#pragma unroll
            for (int c = 0; c < 3; c++) fq[qt][c] = *(const bf16x8*)&qp[c * 32 + g * 8];
        }

        floatx4 o[2][4];
#pragma unroll
        for (int qt = 0; qt < 2; qt++)
#pragma unroll
            for (int vc = 0; vc < 4; vc++) o[qt][vc] = (floatx4){0.f, 0.f, 0.f, 0.f};
        float m[2] = {-1e30f, -1e30f}, l[2] = {0.f, 0.f};

        // prologue: previous compute must be done with LDS before tile-0 issue
        __syncthreads();
#pragma unroll
        for (int i = 0; i < 3; i++) gl_lds16(ksrc0[i], &Ks[0][(w * 3 + i) * 512]);
        ushort8_t vr0 = *(const ushort8_t*)vsrc0[0];
        ushort8_t vr1 = *(const ushort8_t*)vsrc0[1];

        for (int kt = 0; kt < ktb; kt++) {
            int p = kt & 1, np = p ^ 1;
            // A: publish V(kt); B: barrier drains K(kt) async + makes all visible
            *(ushort8_t*)&Vs[p][vdst[0]] = vr0;
            *(ushort8_t*)&Vs[p][vdst[1]] = vr1;
            __syncthreads();
            // C: issue next tile into the other buffer (overlaps with compute)
            if (kt + 1 < ktb) {
                long k1 = (long)(kt + 1) * 64;
#pragma unroll
                for (int i = 0; i < 3; i++)
                    gl_lds16(ksrc0[i] + k1 * kstride[i], &Ks[np][(w * 3 + i) * 512]);
                vr0 = *(const ushort8_t*)(vsrc0[0] + k1);
                vr1 = *(const ushort8_t*)(vsrc0[1] + k1);
            }
            // D: compute tile kt
            if (kt <= ktmax_w) {
                int k0 = kt * 64;
                const unsigned short* Kp = &Ks[p][0];
                const unsigned short* Vp = &Vs[p][0];

                floatx4 st[2][4];
#pragma unroll
                for (int kk = 0; kk < 4; kk++) {
                    const unsigned short* kr = &Kp[(kk * 16 + qi) * 96];
                    bf16x8 fk0 = *(const bf16x8*)&kr[g * 8];
                    bf16x8 fk1 = *(const bf16x8*)&kr[32 + g * 8];
                    bf16x8 fk2 = *(const bf16x8*)&kr[64 + g * 8];
#pragma unroll
                    for (int qt = 0; qt < 2; qt++) {
                        floatx4 s = (floatx4){0.f, 0.f, 0.f, 0.f};
                        s = __builtin_amdgcn_mfma_f32_16x16x32_bf16(fk0, fq[qt][0], s, 0, 0, 0);
                        s = __builtin_amdgcn_mfma_f32_16x16x32_bf16(fk1, fq[qt][1], s, 0, 0, 0);
                        s = __builtin_amdgcn_mfma_f32_16x16x32_bf16(fk2, fq[qt][2], s, 0, 0, 0);
                        st[qt][kk] = s;
                    }
                }

                shortx4 fp[2][4];
#pragma unroll
                for (int qt = 0; qt < 2; qt++) {
                    int qrow = qbase + w * 32 + qt * 16 + qi;
                    bool need_mask = (k0 + 63) > (qbase + w * 32 + qt * 16);  // vs tile MIN row
                    float sv[4][4];
                    float tmax = -3e30f;
#pragma unroll
                    for (int kk = 0; kk < 4; kk++)
#pragma unroll
                        for (int r = 0; r < 4; r++) {
                            float s = st[qt][kk][r] * SCALE2_;   // log2 domain
                            if (need_mask && (k0 + kk * 16 + g * 4 + r) > qrow) s = -1e30f;
                            sv[kk][r] = s;
                            tmax = fmaxf(tmax, s);
                        }
                    tmax = fmaxf(tmax, __shfl_xor(tmax, 16, 64));
                    tmax = fmaxf(tmax, __shfl_xor(tmax, 32, 64));
                    float mnew = fmaxf(m[qt], tmax);
                    float ps = 0.f;
#pragma unroll
                    for (int kk = 0; kk < 4; kk++)
#pragma unroll
                        for (int r = 0; r < 4; r++) {
                            float pv = exp2f(sv[kk][r] - mnew);
                            ps += pv;
                            fp[qt][kk][r] = (short)f2bf(pv);
                        }
                    ps += __shfl_xor(ps, 16, 64);
                    ps += __shfl_xor(ps, 32, 64);
                    if (__any(mnew > m[qt])) {
                        float alpha = exp2f(m[qt] - mnew);
                        float ar[4];
#pragma unroll
                        for (int r = 0; r < 4; r++) ar[r] = __shfl(alpha, (lane & 48) | (g * 4 + r), 64);
#pragma unroll
                        for (int vc = 0; vc < 4; vc++) {
                            o[qt][vc][0] *= ar[0]; o[qt][vc][1] *= ar[1];
                            o[qt][vc][2] *= ar[2]; o[qt][vc][3] *= ar[3];
                        }
                        l[qt] = l[qt] * alpha + ps;
                    } else {
                        l[qt] += ps;
                    }
                    m[qt] = mnew;
                }

#pragma unroll
                for (int kk = 0; kk < 4; kk++) {
                    shortx4 fv[4];
#pragma unroll
                    for (int vc = 0; vc < 4; vc++)
                        fv[vc] = *(const shortx4*)&Vp[(vc * 16 + qi) * 80 + kk * 16 + g * 4];
#pragma unroll
                    for (int qt = 0; qt < 2; qt++)
#pragma unroll
                        for (int vc = 0; vc < 4; vc++)
                            o[qt][vc] = __builtin_amdgcn_mfma_f32_16x16x16bf16_1k(fp[qt][kk], fv[vc], o[qt][vc], 0, 0, 0);
                }
            }
        }

#pragma unroll
        for (int qt = 0; qt < 2; qt++) {
            float lr[4];
#pragma unroll
            for (int r = 0; r < 4; r++) lr[r] = __shfl(l[qt], (lane & 48) | (g * 4 + r), 64);
#pragma unroll
            for (int vc = 0; vc < 4; vc++)
#pragma unroll
                for (int r = 0; r < 4; r++)
                    out[(tok0 + qbase + w * 32 + qt * 16 + g * 4 + r) * HVD + h * VD_ + vc * 16 + qi] =
                        f2bf(o[qt][vc][r] / lr[r]);
        }
    }
}

extern "C" void kernel_launch(void* const* d_in, const int* in_sizes, int n_in,
                              void* d_out, int out_size, void* d_ws, size_t ws_size,
                              hipStream_t stream) {
    const void* hidden = d_in[0];
    const void* cosb   = d_in[1];
    const void* sinb   = d_in[2];
    const void* wq_a   = d_in[3];
    const void* q_ln   = d_in[4];
    const void* wq_b   = d_in[5];
    const void* wkv_a  = d_in[6];
    const void* kv_ln  = d_in[7];
    const void* wkv_b  = d_in[8];
    const void* wo     = d_in[9];

    char* ws = (char*)d_ws;
    size_t off = 0;
    auto alloc = [&](size_t bytes) -> void* {
        void* p = ws + off;
        off += (bytes + 255) & ~(size_t)255;
        return p;
    };
    int* flag                = (int*)alloc(256);
    unsigned short* hbf      = (unsigned short*)alloc((size_t)TOK * HID_ * 2);  // reused as vt later
    unsigned short* wqa_t    = (unsigned short*)alloc((size_t)QRANK_ * HID_ * 2);
    unsigned short* wqb_t    = (unsigned short*)alloc((size_t)HQKD * QRANK_ * 2);
    unsigned short* wkva_t   = (unsigned short*)alloc((size_t)KVRP_PAD * HID_ * 2);
    unsigned short* wkvb_t   = (unsigned short*)alloc((size_t)HKV * KVRANK_ * 2);
    unsigned short* wo_t     = (unsigned short*)alloc((size_t)HID_ * HVD * 2);
    float*          q_a      = (float*)alloc((size_t)TOK * QRANK_ * 4);
    unsigned short* q_a_n    = (unsigned short*)alloc((size_t)TOK * QRANK_ * 2);
    unsigned short* q_raw    = (unsigned short*)alloc((size_t)TOK * HQKD * 2);
    float*          ckv      = (float*)alloc((size_t)TOK * KVRP_PAD * 4);
    unsigned short* kc_n     = (unsigned short*)alloc((size_t)TOK * KVRANK_ * 2);
    unsigned short* kv_raw   = (unsigned short*)alloc((size_t)TOK * HKV * 2);
    unsigned short* krot     = (unsigned short*)alloc((size_t)TOK * ROPE_ * 2);
    unsigned short* attn_o   = (unsigned short*)alloc((size_t)TOK * HVD * 2);
    unsigned short* vt       = hbf;  // hbf dead after the two A-gemms; same elem count

    k_detect<<<1, 64, 0, stream>>>((const unsigned short*)cosb, flag);

    long nh = (long)TOK * HID_;
    k_tobf<<<(int)((nh + 255) / 256), 256, 0, stream>>>(hidden, hbf, nh, flag);

    k_transpose<<<dim3(HID_ / 32, QRANK_ / 32), 256, 0, stream>>>(wq_a, wqa_t, HID_, QRANK_, QRANK_, flag);
    k_transpose<<<dim3(QRANK_ / 32, HQKD / 32), 256, 0, stream>>>(wq_b, wqb_t, QRANK_, HQKD, HQKD, flag);
    k_transpose<<<dim3(HID_ / 32, KVRP_PAD / 32), 256, 0, stream>>>(wkv_a, wkva_t, HID_, KVRP_, KVRP_PAD, flag);
    k_transpose<<<dim3(KVRANK_ / 32, HKV / 32), 256, 0, stream>>>(wkv_b, wkvb_t, KVRANK_, HKV, HKV, flag);
    k_transpose<<<dim3(HVD / 32, HID_ / 32), 256, 0, stream>>>(wo, wo_t, HVD, HID_, HID_, flag);

    // q chain
    k_gemm<<<dim3(QRANK_ / 128, TOK / 128), 256, 0, stream>>>(hbf, wqa_t, q_a, TOK, QRANK_, HID_, 0, flag);
    k_rmsnorm<<<TOK, 256, 0, stream>>>(q_a, QRANK_, QRANK_, q_ln, q_a_n, QRANK_, flag);
    k_gemm<<<dim3(HQKD / 128, TOK / 128), 256, 0, stream>>>(q_a_n, wqb_t, q_raw, TOK, HQKD, QRANK_, 1, flag);

    // kv chain
    k_gemm<<<dim3(KVRP_PAD / 128, TOK / 128), 256, 0, stream>>>(hbf, wkva_t, ckv, TOK, KVRP_PAD, HID_, 0, flag);
    k_rmsnorm<<<TOK, 256, 0, stream>>>(ckv, KVRP_PAD, KVRANK_, kv_ln, kc_n, KVRANK_, flag);
    k_gemm<<<dim3(HKV / 128, TOK / 128), 256, 0, stream>>>(kc_n, wkvb_t, kv_raw, TOK, HKV, KVRANK_, 1, flag);

    // rope
    long nrq = (long)TOK * H_ * 16;
    k_rope_q<<<(int)((nrq + 255) / 256), 256, 0, stream>>>(q_raw, cosb, sinb, flag);
    long nrk = (long)TOK * 16;
    k_rope_k<<<(int)((nrk + 255) / 256), 256, 0, stream>>>(ckv, krot, cosb, sinb, flag);

    // V transpose (into dead hbf buffer), then attention (balanced pairing)
    k_vtrans<<<dim3(S_ / 32, VD_ / 32, B_ * H_), 256, 0, stream>>>(kv_raw, vt);
    k_attn<<<dim3(S_ / 256, H_, B_), 256, 0, stream>>>(q_raw, kv_raw, krot, vt, attn_o);

    // output projection (dtype per detected mode)
    k_gemm<<<dim3(HID_ / 128, TOK / 128), 256, 0, stream>>>(attn_o, wo_t, d_out, TOK, HID_, HVD, 2, flag);
}